// Round 1
// baseline (1224.548 us; speedup 1.0000x reference)
//
#include <hip/hip_runtime.h>
#include <stdint.h>

// CausalSelfAttn: x(4096,2048) -> QKV proj -> 16-head causal attn -> out proj.
// Strategy: bf16 MFMA (16x16x32) for all matmuls; V stored transposed so PV
// B-fragments are contiguous; flash-style online softmax; causal structure
// used directly (mask input ignored - it is exactly tril 0/-1e9).

#define N_TOK   4096
#define D_MODEL 2048
#define N_HEADS 16
#define HD_DIM  128

typedef __attribute__((ext_vector_type(8))) short short8;
typedef __attribute__((ext_vector_type(4))) float f32x4;

static __device__ __forceinline__ unsigned short f2bf(float f) {
    union { float f; uint32_t u; } v; v.f = f;
    uint32_t r = v.u + 0x7fffu + ((v.u >> 16) & 1u);
    return (unsigned short)(r >> 16);
}

static __device__ __forceinline__ void gload_lds16(const void* g, void* l) {
    __builtin_amdgcn_global_load_lds(
        (const __attribute__((address_space(1))) void*)g,
        (__attribute__((address_space(3))) void*)l,
        16, 0, 0);
}

// ---------------- f32 -> bf16 conversion (vectorized, grid-stride) ---------
__global__ void cvt_f32_bf16(const float* __restrict__ src,
                             unsigned short* __restrict__ dst, int n4) {
    int i = blockIdx.x * blockDim.x + threadIdx.x;
    int stride = gridDim.x * blockDim.x;
    for (; i < n4; i += stride) {
        float4 f = reinterpret_cast<const float4*>(src)[i];
        ushort4 o;
        o.x = f2bf(f.x); o.y = f2bf(f.y); o.z = f2bf(f.z); o.w = f2bf(f.w);
        reinterpret_cast<ushort4*>(dst)[i] = o;
    }
}

// ---------------- GEMM: C(MxN) = A(MxK) * B(NxK)^T + bias ------------------
// 128x128 tile, BK=64, 256 threads (4 waves, 2x2), global_load_lds staging,
// LDS XOR-swizzle (byte ^= (row&7)<<4) applied via pre-swizzled global source
// (linear LDS dest) + swizzled ds_read.  All dims assumed %128, K %64.
#define BM 128
#define BN 128
#define BK 64

template<int OUT_BF16, int BIAS_ROW>
__global__ __launch_bounds__(256) void gemm_bt(
    const unsigned short* __restrict__ A, int lda,
    const unsigned short* __restrict__ B, int ldb,
    void* __restrict__ Cv, int ldc,
    const float* __restrict__ bias, int K)
{
    __shared__ __align__(16) unsigned short As[BM * BK];
    __shared__ __align__(16) unsigned short Bs[BN * BK];
    const int tid = threadIdx.x;
    const int w = tid >> 6, l = tid & 63;
    const int wr = w >> 1, wc = w & 1;
    const int l15 = l & 15, l4 = l >> 4;
    const int row0 = blockIdx.y * BM;
    const int col0 = blockIdx.x * BN;

    f32x4 acc[4][4] = {};

    // staging: thread t loads 16B; LDS linear byte = chunk*4096 + t*16
    // source k-byte pre-swizzled so swizzled reads see original data
    const int srow = tid >> 3;                                   // 0..31
    const int ske  = (((tid & 7) * 16) ^ ((srow & 7) << 4)) >> 1; // elements

    for (int kt = 0; kt < K; kt += BK) {
#pragma unroll
        for (int c = 0; c < 4; ++c)
            gload_lds16(A + (size_t)(row0 + c * 32 + srow) * lda + kt + ske,
                        As + c * 2048 + w * 512);
#pragma unroll
        for (int c = 0; c < 4; ++c)
            gload_lds16(B + (size_t)(col0 + c * 32 + srow) * ldb + kt + ske,
                        Bs + c * 2048 + w * 512);
        __syncthreads();
#pragma unroll
        for (int s = 0; s < 2; ++s) {
            short8 af[4], bf[4];
#pragma unroll
            for (int mt = 0; mt < 4; ++mt) {
                int r = wr * 64 + mt * 16 + l15;
                int kb = (s * 64 + l4 * 16) ^ ((r & 7) << 4);
                af[mt] = *reinterpret_cast<const short8*>((const char*)As + r * 128 + kb);
            }
#pragma unroll
            for (int nt = 0; nt < 4; ++nt) {
                int r = wc * 64 + nt * 16 + l15;
                int kb = (s * 64 + l4 * 16) ^ ((r & 7) << 4);
                bf[nt] = *reinterpret_cast<const short8*>((const char*)Bs + r * 128 + kb);
            }
#pragma unroll
            for (int mt = 0; mt < 4; ++mt)
#pragma unroll
                for (int nt = 0; nt < 4; ++nt)
                    acc[mt][nt] = __builtin_amdgcn_mfma_f32_16x16x32_bf16(
                        af[mt], bf[nt], acc[mt][nt], 0, 0, 0);
        }
        __syncthreads();
    }

    // epilogue: C layout col = l&15, row = (l>>4)*4 + reg   [m89-verified]
#pragma unroll
    for (int mt = 0; mt < 4; ++mt)
#pragma unroll
        for (int nt = 0; nt < 4; ++nt) {
            int col = col0 + wc * 64 + nt * 16 + l15;
#pragma unroll
            for (int r_ = 0; r_ < 4; ++r_) {
                int row = row0 + wr * 64 + mt * 16 + l4 * 4 + r_;
                float v = acc[mt][nt][r_] + (BIAS_ROW ? bias[row] : bias[col]);
                if (OUT_BF16)
                    ((unsigned short*)Cv)[(size_t)row * ldc + col] = f2bf(v);
                else
                    ((float*)Cv)[(size_t)row * ldc + col] = v;
            }
        }
}

// ---------------- causal flash attention -----------------------------------
// grid (N/64, H); 256 threads = 4 waves, each wave owns 16 q-rows.
// Q in registers; K,Vt fragments from global (L2-resident per head);
// P staged through wave-private swizzled LDS (C-layout -> A-fragment layout).
__global__ __launch_bounds__(256) void attn_kernel(
    const unsigned short* __restrict__ Qb,
    const unsigned short* __restrict__ Kb,
    const unsigned short* __restrict__ Vtb,
    unsigned short* __restrict__ Ob)
{
    __shared__ __align__(16) unsigned short P_lds[4 * 16 * 64];
    const int tid = threadIdx.x;
    const int w = tid >> 6, l = tid & 63;
    const int l15 = l & 15, l4 = l >> 4;
    const int h = blockIdx.y;
    const int q0 = blockIdx.x * 64;
    const int qw = q0 + w * 16;
    const float scale = 0.088388347648318447f; // 1/sqrt(128)

    short8 qa[4];
#pragma unroll
    for (int s = 0; s < 4; ++s)
        qa[s] = *reinterpret_cast<const short8*>(
            Qb + (size_t)(qw + l15) * D_MODEL + h * HD_DIM + s * 32 + l4 * 8);

    float m[4], lsum[4];
#pragma unroll
    for (int r = 0; r < 4; ++r) { m[r] = -1e30f; lsum[r] = 0.f; }
    f32x4 oacc[8] = {};

    const int nkt = blockIdx.x + 1;
    for (int kt = 0; kt < nkt; ++kt) {
        const int kv0 = kt * 64;
        f32x4 sacc[4] = {};
#pragma unroll
        for (int s = 0; s < 4; ++s)
#pragma unroll
            for (int c = 0; c < 4; ++c) {
                short8 kf = *reinterpret_cast<const short8*>(
                    Kb + (size_t)(kv0 + c * 16 + l15) * D_MODEL + h * HD_DIM + s * 32 + l4 * 8);
                sacc[c] = __builtin_amdgcn_mfma_f32_16x16x32_bf16(qa[s], kf, sacc[c], 0, 0, 0);
            }
        // scale + causal mask
        float sv[4][4];
#pragma unroll
        for (int c = 0; c < 4; ++c) {
            int col = kv0 + c * 16 + l15;
#pragma unroll
            for (int r = 0; r < 4; ++r) {
                int row = qw + l4 * 4 + r;
                sv[c][r] = sacc[c][r] * scale + (col > row ? -1e30f : 0.f);
            }
        }
        // online softmax (rows live across 16 lanes at fixed reg)
        float alpha[4];
#pragma unroll
        for (int r = 0; r < 4; ++r) {
            float mx = fmaxf(fmaxf(sv[0][r], sv[1][r]), fmaxf(sv[2][r], sv[3][r]));
#pragma unroll
            for (int d = 8; d >= 1; d >>= 1) mx = fmaxf(mx, __shfl_xor(mx, d, 16));
            float mnew = fmaxf(m[r], mx);
            alpha[r] = __expf(m[r] - mnew);
            m[r] = mnew;
            float rs = 0.f;
#pragma unroll
            for (int c = 0; c < 4; ++c) {
                float p = __expf(sv[c][r] - mnew);
                sv[c][r] = p;
                rs += p;
            }
#pragma unroll
            for (int d = 8; d >= 1; d >>= 1) rs += __shfl_xor(rs, d, 16);
            lsum[r] = lsum[r] * alpha[r] + rs;
        }
#pragma unroll
        for (int cd = 0; cd < 8; ++cd)
#pragma unroll
            for (int r = 0; r < 4; ++r) oacc[cd][r] *= alpha[r];
        // P -> LDS (bf16, swizzled), wave-private region
#pragma unroll
        for (int c = 0; c < 4; ++c)
#pragma unroll
            for (int r = 0; r < 4; ++r) {
                int prow = l4 * 4 + r;
                int pcolb = (2 * (c * 16 + l15)) ^ ((prow & 7) << 4);
                *(unsigned short*)((char*)P_lds + w * 2048 + prow * 128 + pcolb) =
                    f2bf(sv[c][r]);
            }
        asm volatile("s_waitcnt lgkmcnt(0)" ::: "memory");
        // O += P * V   (A-frag from LDS, B-frag contiguous from Vt)
#pragma unroll
        for (int s2 = 0; s2 < 2; ++s2) {
            int kb = (s2 * 64 + l4 * 16) ^ ((l15 & 7) << 4);
            short8 pa = *reinterpret_cast<const short8*>(
                (const char*)P_lds + w * 2048 + l15 * 128 + kb);
#pragma unroll
            for (int cd = 0; cd < 8; ++cd) {
                short8 vf = *reinterpret_cast<const short8*>(
                    Vtb + (size_t)(h * HD_DIM + cd * 16 + l15) * N_TOK + kv0 + s2 * 32 + l4 * 8);
                oacc[cd] = __builtin_amdgcn_mfma_f32_16x16x32_bf16(pa, vf, oacc[cd], 0, 0, 0);
            }
        }
        asm volatile("s_waitcnt lgkmcnt(0)" ::: "memory");
    }
#pragma unroll
    for (int r = 0; r < 4; ++r) lsum[r] = 1.f / lsum[r];
#pragma unroll
    for (int cd = 0; cd < 8; ++cd)
#pragma unroll
        for (int r = 0; r < 4; ++r) {
            int row = qw + l4 * 4 + r;
            int col = h * HD_DIM + cd * 16 + l15;
            Ob[(size_t)row * D_MODEL + col] = f2bf(oacc[cd][r] * lsum[r]);
        }
}

// ---------------- launch ----------------------------------------------------
extern "C" void kernel_launch(void* const* d_in, const int* in_sizes, int n_in,
                              void* d_out, int out_size, void* d_ws, size_t ws_size,
                              hipStream_t stream) {
    const float* x  = (const float*)d_in[0];
    const float* Wq = (const float*)d_in[2];
    const float* bq = (const float*)d_in[3];
    const float* Wk = (const float*)d_in[4];
    const float* bk = (const float*)d_in[5];
    const float* Wv = (const float*)d_in[6];
    const float* bv = (const float*)d_in[7];
    const float* Wo = (const float*)d_in[8];
    const float* bo = (const float*)d_in[9];

    char* ws = (char*)d_ws;
    unsigned short* xb  = (unsigned short*)(ws);
    unsigned short* Wqb = (unsigned short*)(ws + ((size_t)16 << 20));
    unsigned short* Wkb = (unsigned short*)(ws + ((size_t)24 << 20));
    unsigned short* Wvb = (unsigned short*)(ws + ((size_t)32 << 20));
    unsigned short* Wob = (unsigned short*)(ws + ((size_t)40 << 20));
    unsigned short* Qb  = (unsigned short*)(ws + ((size_t)48 << 20));
    unsigned short* Kb  = (unsigned short*)(ws + ((size_t)64 << 20));
    unsigned short* Vtb = (unsigned short*)(ws + ((size_t)80 << 20));
    unsigned short* Ob  = (unsigned short*)(ws + ((size_t)96 << 20));

    cvt_f32_bf16<<<2048, 256, 0, stream>>>(x,  xb,  (N_TOK * D_MODEL) / 4);
    cvt_f32_bf16<<<1024, 256, 0, stream>>>(Wq, Wqb, (D_MODEL * D_MODEL) / 4);
    cvt_f32_bf16<<<1024, 256, 0, stream>>>(Wk, Wkb, (D_MODEL * D_MODEL) / 4);
    cvt_f32_bf16<<<1024, 256, 0, stream>>>(Wv, Wvb, (D_MODEL * D_MODEL) / 4);
    cvt_f32_bf16<<<1024, 256, 0, stream>>>(Wo, Wob, (D_MODEL * D_MODEL) / 4);

    // Q = x Wq^T + bq ; K = x Wk^T + bk          (4096 x 2048, bias per col)
    gemm_bt<1, 0><<<dim3(D_MODEL / BN, N_TOK / BM), 256, 0, stream>>>(
        xb, D_MODEL, Wqb, D_MODEL, Qb, D_MODEL, bq, D_MODEL);
    gemm_bt<1, 0><<<dim3(D_MODEL / BN, N_TOK / BM), 256, 0, stream>>>(
        xb, D_MODEL, Wkb, D_MODEL, Kb, D_MODEL, bk, D_MODEL);
    // Vt = Wv x^T + bv (stored transposed: 2048 x 4096, bias per row)
    gemm_bt<1, 1><<<dim3(N_TOK / BN, D_MODEL / BM), 256, 0, stream>>>(
        Wvb, D_MODEL, xb, D_MODEL, Vtb, N_TOK, bv, D_MODEL);
    // attention
    attn_kernel<<<dim3(N_TOK / 64, N_HEADS), 256, 0, stream>>>(Qb, Kb, Vtb, Ob);
    // out = O Wo^T + bo  (f32 out)
    gemm_bt<0, 0><<<dim3(D_MODEL / BN, N_TOK / BM), 256, 0, stream>>>(
        Ob, D_MODEL, Wob, D_MODEL, (float*)d_out, D_MODEL, bo, D_MODEL);
}

// Round 2
// 679.452 us; speedup vs baseline: 1.8023x; 1.8023x over previous
//
#include <hip/hip_runtime.h>
#include <stdint.h>

// CausalSelfAttn: x(4096,2048) -> QKV proj -> 16-head causal attn -> out proj.
// R1: attention now stages K/V tiles in LDS (double-buffered, prefetch t+1
// while computing t), shared across the block's 4 waves -> 4x less L2 traffic.
// Longest-first q-tile order to reduce the causal imbalance tail.

#define N_TOK   4096
#define D_MODEL 2048
#define N_HEADS 16
#define HD_DIM  128

typedef __attribute__((ext_vector_type(8))) short short8;
typedef __attribute__((ext_vector_type(4))) float f32x4;

static __device__ __forceinline__ unsigned short f2bf(float f) {
    union { float f; uint32_t u; } v; v.f = f;
    uint32_t r = v.u + 0x7fffu + ((v.u >> 16) & 1u);
    return (unsigned short)(r >> 16);
}

static __device__ __forceinline__ void gload_lds16(const void* g, void* l) {
    __builtin_amdgcn_global_load_lds(
        (const __attribute__((address_space(1))) void*)g,
        (__attribute__((address_space(3))) void*)l,
        16, 0, 0);
}

// ---------------- f32 -> bf16 conversion (vectorized, grid-stride) ---------
__global__ void cvt_f32_bf16(const float* __restrict__ src,
                             unsigned short* __restrict__ dst, int n4) {
    int i = blockIdx.x * blockDim.x + threadIdx.x;
    int stride = gridDim.x * blockDim.x;
    for (; i < n4; i += stride) {
        float4 f = reinterpret_cast<const float4*>(src)[i];
        ushort4 o;
        o.x = f2bf(f.x); o.y = f2bf(f.y); o.z = f2bf(f.z); o.w = f2bf(f.w);
        reinterpret_cast<ushort4*>(dst)[i] = o;
    }
}

// ---------------- GEMM: C(MxN) = A(MxK) * B(NxK)^T + bias ------------------
#define BM 128
#define BN 128
#define BK 64

template<int OUT_BF16, int BIAS_ROW>
__global__ __launch_bounds__(256) void gemm_bt(
    const unsigned short* __restrict__ A, int lda,
    const unsigned short* __restrict__ B, int ldb,
    void* __restrict__ Cv, int ldc,
    const float* __restrict__ bias, int K)
{
    __shared__ __align__(16) unsigned short As[BM * BK];
    __shared__ __align__(16) unsigned short Bs[BN * BK];
    const int tid = threadIdx.x;
    const int w = tid >> 6, l = tid & 63;
    const int wr = w >> 1, wc = w & 1;
    const int l15 = l & 15, l4 = l >> 4;
    const int row0 = blockIdx.y * BM;
    const int col0 = blockIdx.x * BN;

    f32x4 acc[4][4] = {};

    const int srow = tid >> 3;                                    // 0..31
    const int ske  = (((tid & 7) * 16) ^ ((srow & 7) << 4)) >> 1; // elements

    for (int kt = 0; kt < K; kt += BK) {
#pragma unroll
        for (int c = 0; c < 4; ++c)
            gload_lds16(A + (size_t)(row0 + c * 32 + srow) * lda + kt + ske,
                        As + c * 2048 + w * 512);
#pragma unroll
        for (int c = 0; c < 4; ++c)
            gload_lds16(B + (size_t)(col0 + c * 32 + srow) * ldb + kt + ske,
                        Bs + c * 2048 + w * 512);
        __syncthreads();
#pragma unroll
        for (int s = 0; s < 2; ++s) {
            short8 af[4], bf[4];
#pragma unroll
            for (int mt = 0; mt < 4; ++mt) {
                int r = wr * 64 + mt * 16 + l15;
                int kb = (s * 64 + l4 * 16) ^ ((r & 7) << 4);
                af[mt] = *reinterpret_cast<const short8*>((const char*)As + r * 128 + kb);
            }
#pragma unroll
            for (int nt = 0; nt < 4; ++nt) {
                int r = wc * 64 + nt * 16 + l15;
                int kb = (s * 64 + l4 * 16) ^ ((r & 7) << 4);
                bf[nt] = *reinterpret_cast<const short8*>((const char*)Bs + r * 128 + kb);
            }
#pragma unroll
            for (int mt = 0; mt < 4; ++mt)
#pragma unroll
                for (int nt = 0; nt < 4; ++nt)
                    acc[mt][nt] = __builtin_amdgcn_mfma_f32_16x16x32_bf16(
                        af[mt], bf[nt], acc[mt][nt], 0, 0, 0);
        }
        __syncthreads();
    }

#pragma unroll
    for (int mt = 0; mt < 4; ++mt)
#pragma unroll
        for (int nt = 0; nt < 4; ++nt) {
            int col = col0 + wc * 64 + nt * 16 + l15;
#pragma unroll
            for (int r_ = 0; r_ < 4; ++r_) {
                int row = row0 + wr * 64 + mt * 16 + l4 * 4 + r_;
                float v = acc[mt][nt][r_] + (BIAS_ROW ? bias[row] : bias[col]);
                if (OUT_BF16)
                    ((unsigned short*)Cv)[(size_t)row * ldc + col] = f2bf(v);
                else
                    ((float*)Cv)[(size_t)row * ldc + col] = v;
            }
        }
}

// ---------------- causal flash attention -----------------------------------
// grid (N/64, H); 256 threads = 4 waves, each wave owns 16 q-rows.
// K/V tiles staged in LDS (double-buffered, prefetched) shared by all waves;
// XOR-swizzled via pre-swizzled global source (linear LDS dest, rule #21).
__global__ __launch_bounds__(256) void attn_kernel(
    const unsigned short* __restrict__ Qb,
    const unsigned short* __restrict__ Kb,
    const unsigned short* __restrict__ Vtb,
    unsigned short* __restrict__ Ob)
{
    __shared__ __align__(16) unsigned short Ks[2][64 * 128];   // [n-row][d] 256B rows
    __shared__ __align__(16) unsigned short Vs[2][128 * 64];   // [d-row][n] 128B rows
    __shared__ __align__(16) unsigned short P_lds[4 * 16 * 64];
    const int tid = threadIdx.x;
    const int w = tid >> 6, l = tid & 63;
    const int l15 = l & 15, l4 = l >> 4;
    const int h = blockIdx.y;
    const int qi = gridDim.x - 1 - blockIdx.x;  // longest-first
    const int q0 = qi * 64;
    const int qw = q0 + w * 16;
    const float scale = 0.088388347648318447f; // 1/sqrt(128)

    short8 qa[4];
#pragma unroll
    for (int s = 0; s < 4; ++s)
        qa[s] = *reinterpret_cast<const short8*>(
            Qb + (size_t)(qw + l15) * D_MODEL + h * HD_DIM + s * 32 + l4 * 8);

    float m[4], lsum[4];
#pragma unroll
    for (int r = 0; r < 4; ++r) { m[r] = -1e30f; lsum[r] = 0.f; }
    f32x4 oacc[8] = {};

    // staging geometry: 256 threads x 16B; K chunk = 16 rows x 256B,
    // V chunk = 32 rows x 128B; source col pre-swizzled (inverse == forward).
    const int krow_c = tid >> 4;              // 0..15
    const int kcolb  = (tid & 15) * 16;       // byte in 256B row
    const int vrow_c = tid >> 3;              // 0..31
    const int vcolb  = (tid & 7) * 16;        // byte in 128B row

    const int nkt = qi + 1;

    // prologue: stage tile 0 into buf 0
#pragma unroll
    for (int c = 0; c < 4; ++c) {
        int row = c * 16 + krow_c;
        int se = (kcolb ^ ((row & 7) << 4)) >> 1;
        gload_lds16(Kb + (size_t)row * D_MODEL + h * HD_DIM + se,
                    Ks[0] + c * 2048 + w * 512);
    }
#pragma unroll
    for (int c = 0; c < 4; ++c) {
        int row = c * 32 + vrow_c;
        int se = (vcolb ^ ((row & 7) << 4)) >> 1;
        gload_lds16(Vtb + (size_t)(h * HD_DIM + row) * N_TOK + se,
                    Vs[0] + c * 2048 + w * 512);
    }
    __syncthreads();

    int cur = 0;
    for (int kt = 0; kt < nkt; ++kt) {
        // prefetch next tile into the other buffer
        if (kt + 1 < nkt) {
            const int kv1 = (kt + 1) * 64;
#pragma unroll
            for (int c = 0; c < 4; ++c) {
                int row = c * 16 + krow_c;
                int se = (kcolb ^ ((row & 7) << 4)) >> 1;
                gload_lds16(Kb + (size_t)(kv1 + row) * D_MODEL + h * HD_DIM + se,
                            Ks[cur ^ 1] + c * 2048 + w * 512);
            }
#pragma unroll
            for (int c = 0; c < 4; ++c) {
                int row = c * 32 + vrow_c;
                int se = (vcolb ^ ((row & 7) << 4)) >> 1;
                gload_lds16(Vtb + (size_t)(h * HD_DIM + row) * N_TOK + kv1 + se,
                            Vs[cur ^ 1] + c * 2048 + w * 512);
            }
        }

        const int kv0 = kt * 64;
        // QK^T from Ks[cur]
        f32x4 sacc[4] = {};
#pragma unroll
        for (int s = 0; s < 4; ++s)
#pragma unroll
            for (int c = 0; c < 4; ++c) {
                int row = c * 16 + l15;
                int kb = (s * 64 + l4 * 16) ^ ((row & 7) << 4);
                short8 kf = *reinterpret_cast<const short8*>(
                    (const char*)(Ks[cur]) + row * 256 + kb);
                sacc[c] = __builtin_amdgcn_mfma_f32_16x16x32_bf16(qa[s], kf, sacc[c], 0, 0, 0);
            }

        // scale + causal mask
        float sv[4][4];
#pragma unroll
        for (int c = 0; c < 4; ++c) {
            int col = kv0 + c * 16 + l15;
#pragma unroll
            for (int r = 0; r < 4; ++r) {
                int row = qw + l4 * 4 + r;
                sv[c][r] = sacc[c][r] * scale + (col > row ? -1e30f : 0.f);
            }
        }
        // online softmax (rows live across 16 lanes at fixed reg)
        float alpha[4];
#pragma unroll
        for (int r = 0; r < 4; ++r) {
            float mx = fmaxf(fmaxf(sv[0][r], sv[1][r]), fmaxf(sv[2][r], sv[3][r]));
#pragma unroll
            for (int d = 8; d >= 1; d >>= 1) mx = fmaxf(mx, __shfl_xor(mx, d, 16));
            float mnew = fmaxf(m[r], mx);
            alpha[r] = __expf(m[r] - mnew);
            m[r] = mnew;
            float rs = 0.f;
#pragma unroll
            for (int c = 0; c < 4; ++c) {
                float p = __expf(sv[c][r] - mnew);
                sv[c][r] = p;
                rs += p;
            }
#pragma unroll
            for (int d = 8; d >= 1; d >>= 1) rs += __shfl_xor(rs, d, 16);
            lsum[r] = lsum[r] * alpha[r] + rs;
        }
#pragma unroll
        for (int cd = 0; cd < 8; ++cd)
#pragma unroll
            for (int r = 0; r < 4; ++r) oacc[cd][r] *= alpha[r];

        // P -> LDS (bf16, swizzled), wave-private region
#pragma unroll
        for (int c = 0; c < 4; ++c)
#pragma unroll
            for (int r = 0; r < 4; ++r) {
                int prow = l4 * 4 + r;
                int pcolb = (2 * (c * 16 + l15)) ^ ((prow & 7) << 4);
                *(unsigned short*)((char*)P_lds + w * 2048 + prow * 128 + pcolb) =
                    f2bf(sv[c][r]);
            }
        asm volatile("s_waitcnt lgkmcnt(0)" ::: "memory");
        __builtin_amdgcn_sched_barrier(0);

        // O += P * V   (A-frag from P_lds, B-frag from Vs[cur])
#pragma unroll
        for (int s2 = 0; s2 < 2; ++s2) {
            int kb = (s2 * 64 + l4 * 16) ^ ((l15 & 7) << 4);
            short8 pa = *reinterpret_cast<const short8*>(
                (const char*)P_lds + w * 2048 + l15 * 128 + kb);
#pragma unroll
            for (int cd = 0; cd < 8; ++cd) {
                int vrow = cd * 16 + l15;
                int vb = (s2 * 64 + l4 * 16) ^ ((vrow & 7) << 4);
                short8 vf = *reinterpret_cast<const short8*>(
                    (const char*)(Vs[cur]) + vrow * 128 + vb);
                oacc[cd] = __builtin_amdgcn_mfma_f32_16x16x32_bf16(pa, vf, oacc[cd], 0, 0, 0);
            }
        }
        __syncthreads();   // drains vmcnt (prefetch) + lgkm; buffers swap safely
        cur ^= 1;
    }

#pragma unroll
    for (int r = 0; r < 4; ++r) lsum[r] = 1.f / lsum[r];
#pragma unroll
    for (int cd = 0; cd < 8; ++cd)
#pragma unroll
        for (int r = 0; r < 4; ++r) {
            int row = qw + l4 * 4 + r;
            int col = h * HD_DIM + cd * 16 + l15;
            Ob[(size_t)row * D_MODEL + col] = f2bf(oacc[cd][r] * lsum[r]);
        }
}

// ---------------- launch ----------------------------------------------------
extern "C" void kernel_launch(void* const* d_in, const int* in_sizes, int n_in,
                              void* d_out, int out_size, void* d_ws, size_t ws_size,
                              hipStream_t stream) {
    const float* x  = (const float*)d_in[0];
    const float* Wq = (const float*)d_in[2];
    const float* bq = (const float*)d_in[3];
    const float* Wk = (const float*)d_in[4];
    const float* bk = (const float*)d_in[5];
    const float* Wv = (const float*)d_in[6];
    const float* bv = (const float*)d_in[7];
    const float* Wo = (const float*)d_in[8];
    const float* bo = (const float*)d_in[9];

    char* ws = (char*)d_ws;
    unsigned short* xb  = (unsigned short*)(ws);
    unsigned short* Wqb = (unsigned short*)(ws + ((size_t)16 << 20));
    unsigned short* Wkb = (unsigned short*)(ws + ((size_t)24 << 20));
    unsigned short* Wvb = (unsigned short*)(ws + ((size_t)32 << 20));
    unsigned short* Wob = (unsigned short*)(ws + ((size_t)40 << 20));
    unsigned short* Qb  = (unsigned short*)(ws + ((size_t)48 << 20));
    unsigned short* Kb  = (unsigned short*)(ws + ((size_t)64 << 20));
    unsigned short* Vtb = (unsigned short*)(ws + ((size_t)80 << 20));
    unsigned short* Ob  = (unsigned short*)(ws + ((size_t)96 << 20));

    cvt_f32_bf16<<<2048, 256, 0, stream>>>(x,  xb,  (N_TOK * D_MODEL) / 4);
    cvt_f32_bf16<<<1024, 256, 0, stream>>>(Wq, Wqb, (D_MODEL * D_MODEL) / 4);
    cvt_f32_bf16<<<1024, 256, 0, stream>>>(Wk, Wkb, (D_MODEL * D_MODEL) / 4);
    cvt_f32_bf16<<<1024, 256, 0, stream>>>(Wv, Wvb, (D_MODEL * D_MODEL) / 4);
    cvt_f32_bf16<<<1024, 256, 0, stream>>>(Wo, Wob, (D_MODEL * D_MODEL) / 4);

    // Q = x Wq^T + bq ; K = x Wk^T + bk          (4096 x 2048, bias per col)
    gemm_bt<1, 0><<<dim3(D_MODEL / BN, N_TOK / BM), 256, 0, stream>>>(
        xb, D_MODEL, Wqb, D_MODEL, Qb, D_MODEL, bq, D_MODEL);
    gemm_bt<1, 0><<<dim3(D_MODEL / BN, N_TOK / BM), 256, 0, stream>>>(
        xb, D_MODEL, Wkb, D_MODEL, Kb, D_MODEL, bk, D_MODEL);
    // Vt = Wv x^T + bv (stored transposed: 2048 x 4096, bias per row)
    gemm_bt<1, 1><<<dim3(N_TOK / BN, D_MODEL / BM), 256, 0, stream>>>(
        Wvb, D_MODEL, xb, D_MODEL, Vtb, N_TOK, bv, D_MODEL);
    // attention
    attn_kernel<<<dim3(N_TOK / 64, N_HEADS), 256, 0, stream>>>(Qb, Kb, Vtb, Ob);
    // out = O Wo^T + bo  (f32 out)
    gemm_bt<0, 0><<<dim3(D_MODEL / BN, N_TOK / BM), 256, 0, stream>>>(
        Ob, D_MODEL, Wob, D_MODEL, (float*)d_out, D_MODEL, bo, D_MODEL);
}

// Round 3
// 595.568 us; speedup vs baseline: 2.0561x; 1.1408x over previous
//
#include <hip/hip_runtime.h>
#include <stdint.h>

// CausalSelfAttn: x(4096,2048) -> QKV proj -> 16-head causal attn -> out proj.
// R2: attention rewritten to swapped-QK^T 32x32 MFMA structure: lane-local
// softmax (no per-row shuffle reduces), cvt_pk_bf16 + permlane32_swap P
// redistribution (no P_lds), base-2 exp, defer-max rescale (T13).

#define N_TOK   4096
#define D_MODEL 2048
#define N_HEADS 16
#define HD_DIM  128

typedef __attribute__((ext_vector_type(8))) short short8;
typedef __attribute__((ext_vector_type(4))) float f32x4;
typedef __attribute__((ext_vector_type(16))) float f32x16;

static __device__ __forceinline__ unsigned short f2bf(float f) {
    union { float f; uint32_t u; } v; v.f = f;
    uint32_t r = v.u + 0x7fffu + ((v.u >> 16) & 1u);
    return (unsigned short)(r >> 16);
}

static __device__ __forceinline__ float exp2fast(float x) {
    float r; asm("v_exp_f32 %0, %1" : "=v"(r) : "v"(x)); return r;
}

static __device__ __forceinline__ unsigned cvtpk_bf16(float lo, float hi) {
    unsigned r; asm("v_cvt_pk_bf16_f32 %0, %1, %2" : "=v"(r) : "v"(lo), "v"(hi));
    return r;
}

static __device__ __forceinline__ void gload_lds16(const void* g, void* l) {
    __builtin_amdgcn_global_load_lds(
        (const __attribute__((address_space(1))) void*)g,
        (__attribute__((address_space(3))) void*)l,
        16, 0, 0);
}

// ---------------- f32 -> bf16 conversion (vectorized, grid-stride) ---------
__global__ void cvt_f32_bf16(const float* __restrict__ src,
                             unsigned short* __restrict__ dst, int n4) {
    int i = blockIdx.x * blockDim.x + threadIdx.x;
    int stride = gridDim.x * blockDim.x;
    for (; i < n4; i += stride) {
        float4 f = reinterpret_cast<const float4*>(src)[i];
        ushort4 o;
        o.x = f2bf(f.x); o.y = f2bf(f.y); o.z = f2bf(f.z); o.w = f2bf(f.w);
        reinterpret_cast<ushort4*>(dst)[i] = o;
    }
}

// ---------------- GEMM: C(MxN) = A(MxK) * B(NxK)^T + bias ------------------
#define BM 128
#define BN 128
#define BK 64

template<int OUT_BF16, int BIAS_ROW>
__global__ __launch_bounds__(256) void gemm_bt(
    const unsigned short* __restrict__ A, int lda,
    const unsigned short* __restrict__ B, int ldb,
    void* __restrict__ Cv, int ldc,
    const float* __restrict__ bias, int K)
{
    __shared__ __align__(16) unsigned short As[BM * BK];
    __shared__ __align__(16) unsigned short Bs[BN * BK];
    const int tid = threadIdx.x;
    const int w = tid >> 6, l = tid & 63;
    const int wr = w >> 1, wc = w & 1;
    const int l15 = l & 15, l4 = l >> 4;
    const int row0 = blockIdx.y * BM;
    const int col0 = blockIdx.x * BN;

    f32x4 acc[4][4] = {};

    const int srow = tid >> 3;                                    // 0..31
    const int ske  = (((tid & 7) * 16) ^ ((srow & 7) << 4)) >> 1; // elements

    for (int kt = 0; kt < K; kt += BK) {
#pragma unroll
        for (int c = 0; c < 4; ++c)
            gload_lds16(A + (size_t)(row0 + c * 32 + srow) * lda + kt + ske,
                        As + c * 2048 + w * 512);
#pragma unroll
        for (int c = 0; c < 4; ++c)
            gload_lds16(B + (size_t)(col0 + c * 32 + srow) * ldb + kt + ske,
                        Bs + c * 2048 + w * 512);
        __syncthreads();
#pragma unroll
        for (int s = 0; s < 2; ++s) {
            short8 af[4], bf[4];
#pragma unroll
            for (int mt = 0; mt < 4; ++mt) {
                int r = wr * 64 + mt * 16 + l15;
                int kb = (s * 64 + l4 * 16) ^ ((r & 7) << 4);
                af[mt] = *reinterpret_cast<const short8*>((const char*)As + r * 128 + kb);
            }
#pragma unroll
            for (int nt = 0; nt < 4; ++nt) {
                int r = wc * 64 + nt * 16 + l15;
                int kb = (s * 64 + l4 * 16) ^ ((r & 7) << 4);
                bf[nt] = *reinterpret_cast<const short8*>((const char*)Bs + r * 128 + kb);
            }
#pragma unroll
            for (int mt = 0; mt < 4; ++mt)
#pragma unroll
                for (int nt = 0; nt < 4; ++nt)
                    acc[mt][nt] = __builtin_amdgcn_mfma_f32_16x16x32_bf16(
                        af[mt], bf[nt], acc[mt][nt], 0, 0, 0);
        }
        __syncthreads();
    }

#pragma unroll
    for (int mt = 0; mt < 4; ++mt)
#pragma unroll
        for (int nt = 0; nt < 4; ++nt) {
            int col = col0 + wc * 64 + nt * 16 + l15;
#pragma unroll
            for (int r_ = 0; r_ < 4; ++r_) {
                int row = row0 + wr * 64 + mt * 16 + l4 * 4 + r_;
                float v = acc[mt][nt][r_] + (BIAS_ROW ? bias[row] : bias[col]);
                if (OUT_BF16)
                    ((unsigned short*)Cv)[(size_t)row * ldc + col] = f2bf(v);
                else
                    ((float*)Cv)[(size_t)row * ldc + col] = v;
            }
        }
}

// ---------------- causal flash attention (swapped-QK^T, 32x32) -------------
// grid (N/128, H); 256 threads = 4 waves, each wave owns 32 q-rows.
// S^T = mfma(K, Q): lane holds P[kv set] for q-row lane&31 -> in-lane softmax.
// P -> PV A-frags via v_cvt_pk_bf16_f32 + v_permlane32_swap_b32.
__global__ __launch_bounds__(256) void attn_kernel(
    const unsigned short* __restrict__ Qb,
    const unsigned short* __restrict__ Kb,
    const unsigned short* __restrict__ Vtb,
    unsigned short* __restrict__ Ob)
{
    __shared__ __align__(16) unsigned short Ks[2][64 * 128];  // [kv][d] 256B rows
    __shared__ __align__(16) unsigned short Vs[2][128 * 64];  // [d][kv] 128B rows
    const int tid = threadIdx.x;
    const int w = tid >> 6, l = tid & 63;
    const int l31 = l & 31, hi = l >> 5;
    const int h = blockIdx.y;
    const int qi = gridDim.x - 1 - blockIdx.x;   // longest-first
    const int q0 = qi * 128;
    const int qw = q0 + w * 32;
    const float scale2 = 0.12753139f;            // (1/sqrt(128)) * log2(e)

    // Q fragments (B-operand): col=q=l31, k-slice = hi*8+j at d = s*16+hi*8
    short8 qreg[8];
#pragma unroll
    for (int s = 0; s < 8; ++s)
        qreg[s] = *reinterpret_cast<const short8*>(
            Qb + (size_t)(qw + l31) * D_MODEL + h * HD_DIM + s * 16 + hi * 8);

    float m = -1e30f, lsum = 0.f;
    f32x16 oacc[4] = {};

    const int nkt = 2 * qi + 2;

    // staging: K swizzle f(row)=row&15 (16 slots/256B row); V f(row)=row&7
    auto stage = [&](int kt, int buf) {
        const int kv0s = kt * 64;
#pragma unroll
        for (int c = 0; c < 4; ++c) {
            int row = c * 16 + w * 4 + (l >> 4);
            int slot = (l & 15) ^ (row & 15);
            gload_lds16(Kb + (size_t)(kv0s + row) * D_MODEL + h * HD_DIM + slot * 8,
                        Ks[buf] + c * 2048 + w * 512);
        }
#pragma unroll
        for (int c = 0; c < 4; ++c) {
            int row = c * 32 + w * 8 + (l >> 3);
            int slot = (l & 7) ^ (row & 7);
            gload_lds16(Vtb + (size_t)(h * HD_DIM + row) * N_TOK + kv0s + slot * 8,
                        Vs[buf] + c * 2048 + w * 512);
        }
    };

    stage(0, 0);
    __syncthreads();

    int cur = 0;
    for (int kt = 0; kt < nkt; ++kt) {
        if (kt + 1 < nkt) stage(kt + 1, cur ^ 1);
        const int kv0 = kt * 64;

        // S^T = K * Q^T : sacc[a] covers kv rows a*32..a*32+31
        f32x16 sacc[2] = {};
#pragma unroll
        for (int s = 0; s < 8; ++s)
#pragma unroll
            for (int a = 0; a < 2; ++a) {
                int row = a * 32 + l31;
                int slot = (2 * s + hi) ^ (row & 15);
                short8 kf = *reinterpret_cast<const short8*>(
                    (const char*)Ks[cur] + row * 256 + slot * 16);
                sacc[a] = __builtin_amdgcn_mfma_f32_32x32x16_bf16(
                    kf, qreg[s], sacc[a], 0, 0, 0);
            }

        // mask + row-max (raw domain); lane's scores all belong to q = qw+l31
        float tmax = -1e30f;
        if (kv0 + 64 > qw) {
#pragma unroll
            for (int a = 0; a < 2; ++a)
#pragma unroll
                for (int r = 0; r < 16; ++r) {
                    int kvl = a * 32 + (r & 3) + 8 * (r >> 2) + 4 * hi;
                    float x = sacc[a][r];
                    x = (kv0 + kvl > qw + l31) ? -1e30f : x;
                    sacc[a][r] = x;
                    tmax = fmaxf(tmax, x);
                }
        } else {
#pragma unroll
            for (int a = 0; a < 2; ++a)
#pragma unroll
                for (int r = 0; r < 16; ++r) tmax = fmaxf(tmax, sacc[a][r]);
        }
        tmax = fmaxf(tmax, __shfl_xor(tmax, 32));

        // defer-max rescale (T13): thr = 8 nats = 90.2 raw units
        if (__any(tmax > m + 90.2f)) {
            float mnew = fmaxf(m, tmax);
            float alpha = exp2fast((m - mnew) * scale2);
            m = mnew;
            lsum *= alpha;
#pragma unroll
            for (int r = 0; r < 16; ++r) {
                float ar = __shfl(alpha, (r & 3) + 8 * (r >> 2) + 4 * hi, 32);
#pragma unroll
                for (int cb = 0; cb < 4; ++cb) oacc[cb][r] *= ar;
            }
        }

        const float mc = m * scale2;
        float rsum = 0.f;
#pragma unroll
        for (int a = 0; a < 2; ++a)
#pragma unroll
            for (int r = 0; r < 16; ++r) {
                float p = exp2fast(fmaf(sacc[a][r], scale2, -mc));
                sacc[a][r] = p;
                rsum += p;
            }
        rsum += __shfl_xor(rsum, 32);
        lsum += rsum;

        // PV: for step st (kv 16-slice), assemble P A-frag via cvt_pk+permlane.
        // value(st,h,e) lives at acc a=st>>1, reg 4*(2*(st&1)+h)+(e&3), half e>>2
#pragma unroll
        for (int st = 0; st < 4; ++st) {
            const int sl = st & 1, a = st >> 1;
            unsigned A0 = cvtpk_bf16(sacc[a][8 * sl + 0], sacc[a][8 * sl + 1]);
            unsigned A1 = cvtpk_bf16(sacc[a][8 * sl + 2], sacc[a][8 * sl + 3]);
            unsigned B0 = cvtpk_bf16(sacc[a][8 * sl + 4], sacc[a][8 * sl + 5]);
            unsigned B1 = cvtpk_bf16(sacc[a][8 * sl + 6], sacc[a][8 * sl + 7]);
            asm volatile("v_permlane32_swap_b32 %0, %1" : "+v"(A0), "+v"(B0));
            asm volatile("v_permlane32_swap_b32 %0, %1" : "+v"(A1), "+v"(B1));
            union { unsigned u[4]; short8 s8; } pu;
            pu.u[0] = A0; pu.u[1] = A1; pu.u[2] = B0; pu.u[3] = B1;
#pragma unroll
            for (int cb = 0; cb < 4; ++cb) {
                int row = cb * 32 + l31;
                int slot = (2 * st + hi) ^ (row & 7);
                short8 vf = *reinterpret_cast<const short8*>(
                    (const char*)Vs[cur] + row * 128 + slot * 16);
                oacc[cb] = __builtin_amdgcn_mfma_f32_32x32x16_bf16(
                    pu.s8, vf, oacc[cb], 0, 0, 0);
            }
        }
        __syncthreads();   // drains prefetch vmcnt + lgkm; safe buffer swap
        cur ^= 1;
    }

    // epilogue: oacc row -> q = qw + (r&3)+8*(r>>2)+4*hi ; col d = cb*32+l31
    float linv = 1.f / lsum;
#pragma unroll
    for (int r = 0; r < 16; ++r) {
        int jr = (r & 3) + 8 * (r >> 2) + 4 * hi;
        float lr = __shfl(linv, jr, 32);
        int qrow = qw + jr;
#pragma unroll
        for (int cb = 0; cb < 4; ++cb)
            Ob[(size_t)qrow * D_MODEL + h * HD_DIM + cb * 32 + l31] =
                f2bf(oacc[cb][r] * lr);
    }
}

// ---------------- launch ----------------------------------------------------
extern "C" void kernel_launch(void* const* d_in, const int* in_sizes, int n_in,
                              void* d_out, int out_size, void* d_ws, size_t ws_size,
                              hipStream_t stream) {
    const float* x  = (const float*)d_in[0];
    const float* Wq = (const float*)d_in[2];
    const float* bq = (const float*)d_in[3];
    const float* Wk = (const float*)d_in[4];
    const float* bk = (const float*)d_in[5];
    const float* Wv = (const float*)d_in[6];
    const float* bv = (const float*)d_in[7];
    const float* Wo = (const float*)d_in[8];
    const float* bo = (const float*)d_in[9];

    char* ws = (char*)d_ws;
    unsigned short* xb  = (unsigned short*)(ws);
    unsigned short* Wqb = (unsigned short*)(ws + ((size_t)16 << 20));
    unsigned short* Wkb = (unsigned short*)(ws + ((size_t)24 << 20));
    unsigned short* Wvb = (unsigned short*)(ws + ((size_t)32 << 20));
    unsigned short* Wob = (unsigned short*)(ws + ((size_t)40 << 20));
    unsigned short* Qb  = (unsigned short*)(ws + ((size_t)48 << 20));
    unsigned short* Kb  = (unsigned short*)(ws + ((size_t)64 << 20));
    unsigned short* Vtb = (unsigned short*)(ws + ((size_t)80 << 20));
    unsigned short* Ob  = (unsigned short*)(ws + ((size_t)96 << 20));

    cvt_f32_bf16<<<2048, 256, 0, stream>>>(x,  xb,  (N_TOK * D_MODEL) / 4);
    cvt_f32_bf16<<<1024, 256, 0, stream>>>(Wq, Wqb, (D_MODEL * D_MODEL) / 4);
    cvt_f32_bf16<<<1024, 256, 0, stream>>>(Wk, Wkb, (D_MODEL * D_MODEL) / 4);
    cvt_f32_bf16<<<1024, 256, 0, stream>>>(Wv, Wvb, (D_MODEL * D_MODEL) / 4);
    cvt_f32_bf16<<<1024, 256, 0, stream>>>(Wo, Wob, (D_MODEL * D_MODEL) / 4);

    gemm_bt<1, 0><<<dim3(D_MODEL / BN, N_TOK / BM), 256, 0, stream>>>(
        xb, D_MODEL, Wqb, D_MODEL, Qb, D_MODEL, bq, D_MODEL);
    gemm_bt<1, 0><<<dim3(D_MODEL / BN, N_TOK / BM), 256, 0, stream>>>(
        xb, D_MODEL, Wkb, D_MODEL, Kb, D_MODEL, bk, D_MODEL);
    gemm_bt<1, 1><<<dim3(N_TOK / BN, D_MODEL / BM), 256, 0, stream>>>(
        Wvb, D_MODEL, xb, D_MODEL, Vtb, N_TOK, bv, D_MODEL);

    attn_kernel<<<dim3(N_TOK / 128, N_HEADS), 256, 0, stream>>>(Qb, Kb, Vtb, Ob);

    gemm_bt<0, 0><<<dim3(D_MODEL / BN, N_TOK / BM), 256, 0, stream>>>(
        Ob, D_MODEL, Wob, D_MODEL, (float*)d_out, D_MODEL, bo, D_MODEL);
}

// Round 4
// 480.558 us; speedup vs baseline: 2.5482x; 1.2393x over previous
//
#include <hip/hip_runtime.h>
#include <stdint.h>

// CausalSelfAttn: x(4096,2048) -> QKV proj -> 16-head causal attn -> out proj.
// R3: attention re-gridded for occupancy: 2-wave blocks (64 q-rows), 1024
// blocks all-resident, single-buffered 32KB LDS (5 blocks/CU, ~10 waves/CU);
// XCD-bijective swizzle so each XCD's L2 holds ~2 heads of K/V. GEMMs get the
// same XCD swizzle. Softmax: swapped-QK^T 32x32, lane-local, defer-max.

#define N_TOK   4096
#define D_MODEL 2048
#define N_HEADS 16
#define HD_DIM  128

typedef __attribute__((ext_vector_type(8))) short short8;
typedef __attribute__((ext_vector_type(4))) float f32x4;
typedef __attribute__((ext_vector_type(16))) float f32x16;

static __device__ __forceinline__ unsigned short f2bf(float f) {
    union { float f; uint32_t u; } v; v.f = f;
    uint32_t r = v.u + 0x7fffu + ((v.u >> 16) & 1u);
    return (unsigned short)(r >> 16);
}

static __device__ __forceinline__ float exp2fast(float x) {
    float r; asm("v_exp_f32 %0, %1" : "=v"(r) : "v"(x)); return r;
}

static __device__ __forceinline__ unsigned cvtpk_bf16(float lo, float hi) {
    unsigned r; asm("v_cvt_pk_bf16_f32 %0, %1, %2" : "=v"(r) : "v"(lo), "v"(hi));
    return r;
}

static __device__ __forceinline__ void gload_lds16(const void* g, void* l) {
    __builtin_amdgcn_global_load_lds(
        (const __attribute__((address_space(1))) void*)g,
        (__attribute__((address_space(3))) void*)l,
        16, 0, 0);
}

// ---------------- f32 -> bf16 conversion (vectorized, grid-stride) ---------
__global__ void cvt_f32_bf16(const float* __restrict__ src,
                             unsigned short* __restrict__ dst, int n4) {
    int i = blockIdx.x * blockDim.x + threadIdx.x;
    int stride = gridDim.x * blockDim.x;
    for (; i < n4; i += stride) {
        float4 f = reinterpret_cast<const float4*>(src)[i];
        ushort4 o;
        o.x = f2bf(f.x); o.y = f2bf(f.y); o.z = f2bf(f.z); o.w = f2bf(f.w);
        reinterpret_cast<ushort4*>(dst)[i] = o;
    }
}

// ---------------- GEMM: C(MxN) = A(MxK) * B(NxK)^T + bias ------------------
#define BM 128
#define BN 128
#define BK 64

template<int OUT_BF16, int BIAS_ROW>
__global__ __launch_bounds__(256) void gemm_bt(
    const unsigned short* __restrict__ A, int lda,
    const unsigned short* __restrict__ B, int ldb,
    void* __restrict__ Cv, int ldc,
    const float* __restrict__ bias, int K)
{
    __shared__ __align__(16) unsigned short As[BM * BK];
    __shared__ __align__(16) unsigned short Bs[BN * BK];
    const int tid = threadIdx.x;
    const int w = tid >> 6, l = tid & 63;
    const int wr = w >> 1, wc = w & 1;
    const int l15 = l & 15, l4 = l >> 4;

    // XCD-bijective swizzle (nwg % 8 == 0 for all our launches)
    const int nwg = gridDim.x * gridDim.y;
    int bid = blockIdx.y * gridDim.x + blockIdx.x;
    bid = (bid & 7) * (nwg >> 3) + (bid >> 3);
    const int row0 = (bid / gridDim.x) * BM;
    const int col0 = (bid % gridDim.x) * BN;

    f32x4 acc[4][4] = {};

    const int srow = tid >> 3;                                    // 0..31
    const int ske  = (((tid & 7) * 16) ^ ((srow & 7) << 4)) >> 1; // elements

    for (int kt = 0; kt < K; kt += BK) {
#pragma unroll
        for (int c = 0; c < 4; ++c)
            gload_lds16(A + (size_t)(row0 + c * 32 + srow) * lda + kt + ske,
                        As + c * 2048 + w * 512);
#pragma unroll
        for (int c = 0; c < 4; ++c)
            gload_lds16(B + (size_t)(col0 + c * 32 + srow) * ldb + kt + ske,
                        Bs + c * 2048 + w * 512);
        __syncthreads();
#pragma unroll
        for (int s = 0; s < 2; ++s) {
            short8 af[4], bf[4];
#pragma unroll
            for (int mt = 0; mt < 4; ++mt) {
                int r = wr * 64 + mt * 16 + l15;
                int kb = (s * 64 + l4 * 16) ^ ((r & 7) << 4);
                af[mt] = *reinterpret_cast<const short8*>((const char*)As + r * 128 + kb);
            }
#pragma unroll
            for (int nt = 0; nt < 4; ++nt) {
                int r = wc * 64 + nt * 16 + l15;
                int kb = (s * 64 + l4 * 16) ^ ((r & 7) << 4);
                bf[nt] = *reinterpret_cast<const short8*>((const char*)Bs + r * 128 + kb);
            }
#pragma unroll
            for (int mt = 0; mt < 4; ++mt)
#pragma unroll
                for (int nt = 0; nt < 4; ++nt)
                    acc[mt][nt] = __builtin_amdgcn_mfma_f32_16x16x32_bf16(
                        af[mt], bf[nt], acc[mt][nt], 0, 0, 0);
        }
        __syncthreads();
    }

#pragma unroll
    for (int mt = 0; mt < 4; ++mt)
#pragma unroll
        for (int nt = 0; nt < 4; ++nt) {
            int col = col0 + wc * 64 + nt * 16 + l15;
#pragma unroll
            for (int r_ = 0; r_ < 4; ++r_) {
                int row = row0 + wr * 64 + mt * 16 + l4 * 4 + r_;
                float v = acc[mt][nt][r_] + (BIAS_ROW ? bias[row] : bias[col]);
                if (OUT_BF16)
                    ((unsigned short*)Cv)[(size_t)row * ldc + col] = f2bf(v);
                else
                    ((float*)Cv)[(size_t)row * ldc + col] = v;
            }
        }
}

// ---------------- causal flash attention (swapped-QK^T, 32x32) -------------
// 1024 blocks x 128 threads (2 waves, 32 q-rows each). Single-buffered K/V
// LDS (32KB -> 5 blocks/CU). Work id XCD-swizzled: each XCD covers 2 heads
// (K/V working set ~4MB = its L2), longest q-tiles first within the head.
__global__ __launch_bounds__(128) void attn_kernel(
    const unsigned short* __restrict__ Qb,
    const unsigned short* __restrict__ Kb,
    const unsigned short* __restrict__ Vtb,
    unsigned short* __restrict__ Ob)
{
    __shared__ __align__(16) unsigned short Ks[64 * 128];  // [kv][d] 256B rows
    __shared__ __align__(16) unsigned short Vs[128 * 64];  // [d][kv] 128B rows
    const int tid = threadIdx.x;
    const int w = tid >> 6, l = tid & 63;
    const int l31 = l & 31, hi = l >> 5;

    // XCD-bijective remap of (head, qtile): 1024 work items, 128 per XCD
    int bid = blockIdx.y * gridDim.x + blockIdx.x;
    bid = (bid & 7) * 128 + (bid >> 3);
    const int h = bid >> 6;
    const int qi = 63 - (bid & 63);             // longest-first within head
    const int q0 = qi * 64;
    const int qw = q0 + w * 32;
    const float scale2 = 0.12753139f;           // (1/sqrt(128)) * log2(e)

    short8 qreg[8];
#pragma unroll
    for (int s = 0; s < 8; ++s)
        qreg[s] = *reinterpret_cast<const short8*>(
            Qb + (size_t)(qw + l31) * D_MODEL + h * HD_DIM + s * 16 + hi * 8);

    float m = -1e30f, lsum = 0.f;
    f32x16 oacc[4] = {};

    const int nkt = qi + 1;

    // staging (128 threads x 16B = 2KB/chunk, 8 chunks each for K and V)
    // K swizzle f(row)=row&15 (16x16B slots/row); V f(row)=row&7 (8 slots)
    const int krow_c = tid >> 4;               // 0..7 within chunk
    const int kslot  = tid & 15;
    const int vrow_c = tid >> 3;               // 0..15 within chunk
    const int vslot  = tid & 7;

    for (int kt = 0; kt < nkt; ++kt) {
        const int kv0 = kt * 64;
        if (kt) __syncthreads();               // prev iter done reading LDS
#pragma unroll
        for (int c = 0; c < 8; ++c) {
            int row = c * 8 + krow_c;
            gload_lds16(Kb + (size_t)(kv0 + row) * D_MODEL + h * HD_DIM
                           + (kslot ^ (row & 15)) * 8,
                        Ks + c * 1024 + w * 512);
        }
#pragma unroll
        for (int c = 0; c < 8; ++c) {
            int row = c * 16 + vrow_c;
            gload_lds16(Vtb + (size_t)(h * HD_DIM + row) * N_TOK + kv0
                            + (vslot ^ (row & 7)) * 8,
                        Vs + c * 1024 + w * 512);
        }
        __syncthreads();                       // stage complete (vmcnt drained)

        // S^T = K * Q^T : sacc[a] covers kv rows a*32..a*32+31
        f32x16 sacc[2] = {};
#pragma unroll
        for (int s = 0; s < 8; ++s)
#pragma unroll
            for (int a = 0; a < 2; ++a) {
                int row = a * 32 + l31;
                int slot = (2 * s + hi) ^ (row & 15);
                short8 kf = *reinterpret_cast<const short8*>(
                    (const char*)Ks + row * 256 + slot * 16);
                sacc[a] = __builtin_amdgcn_mfma_f32_32x32x16_bf16(
                    kf, qreg[s], sacc[a], 0, 0, 0);
            }

        // mask + row-max (raw domain); lane's scores belong to q = qw+l31
        float tmax = -1e30f;
        if (kv0 + 64 > qw) {
#pragma unroll
            for (int a = 0; a < 2; ++a)
#pragma unroll
                for (int r = 0; r < 16; ++r) {
                    int kvl = a * 32 + (r & 3) + 8 * (r >> 2) + 4 * hi;
                    float x = sacc[a][r];
                    x = (kv0 + kvl > qw + l31) ? -1e30f : x;
                    sacc[a][r] = x;
                    tmax = fmaxf(tmax, x);
                }
        } else {
#pragma unroll
            for (int a = 0; a < 2; ++a)
#pragma unroll
                for (int r = 0; r < 16; ++r) tmax = fmaxf(tmax, sacc[a][r]);
        }
        tmax = fmaxf(tmax, __shfl_xor(tmax, 32));

        // defer-max rescale (T13): thr = 8 nats = 90.2 raw units
        if (__any(tmax > m + 90.2f)) {
            float mnew = fmaxf(m, tmax);
            float alpha = exp2fast((m - mnew) * scale2);
            m = mnew;
            lsum *= alpha;
#pragma unroll
            for (int r = 0; r < 16; ++r) {
                float ar = __shfl(alpha, (r & 3) + 8 * (r >> 2) + 4 * hi, 32);
#pragma unroll
                for (int cb = 0; cb < 4; ++cb) oacc[cb][r] *= ar;
            }
        }

        const float mc = m * scale2;
        float rsum = 0.f;
#pragma unroll
        for (int a = 0; a < 2; ++a)
#pragma unroll
            for (int r = 0; r < 16; ++r) {
                float p = exp2fast(fmaf(sacc[a][r], scale2, -mc));
                sacc[a][r] = p;
                rsum += p;
            }
        rsum += __shfl_xor(rsum, 32);
        lsum += rsum;

        // PV: assemble P A-frags via cvt_pk + permlane32_swap
        // value(st,h,e): acc a=st>>1, reg 4*(2*(st&1)+h)+(e&3), half e>>2
#pragma unroll
        for (int st = 0; st < 4; ++st) {
            const int sl = st & 1, a = st >> 1;
            unsigned A0 = cvtpk_bf16(sacc[a][8 * sl + 0], sacc[a][8 * sl + 1]);
            unsigned A1 = cvtpk_bf16(sacc[a][8 * sl + 2], sacc[a][8 * sl + 3]);
            unsigned B0 = cvtpk_bf16(sacc[a][8 * sl + 4], sacc[a][8 * sl + 5]);
            unsigned B1 = cvtpk_bf16(sacc[a][8 * sl + 6], sacc[a][8 * sl + 7]);
            asm volatile("v_permlane32_swap_b32 %0, %1" : "+v"(A0), "+v"(B0));
            asm volatile("v_permlane32_swap_b32 %0, %1" : "+v"(A1), "+v"(B1));
            union { unsigned u[4]; short8 s8; } pu;
            pu.u[0] = A0; pu.u[1] = A1; pu.u[2] = B0; pu.u[3] = B1;
#pragma unroll
            for (int cb = 0; cb < 4; ++cb) {
                int row = cb * 32 + l31;
                int slot = (2 * st + hi) ^ (row & 7);
                short8 vf = *reinterpret_cast<const short8*>(
                    (const char*)Vs + row * 128 + slot * 16);
                oacc[cb] = __builtin_amdgcn_mfma_f32_32x32x16_bf16(
                    pu.s8, vf, oacc[cb], 0, 0, 0);
            }
        }
    }

    // epilogue: oacc row -> q = qw + (r&3)+8*(r>>2)+4*hi ; col d = cb*32+l31
    float linv = 1.f / lsum;
#pragma unroll
    for (int r = 0; r < 16; ++r) {
        int jr = (r & 3) + 8 * (r >> 2) + 4 * hi;
        float lr = __shfl(linv, jr, 32);
        int qrow = qw + jr;
#pragma unroll
        for (int cb = 0; cb < 4; ++cb)
            Ob[(size_t)qrow * D_MODEL + h * HD_DIM + cb * 32 + l31] =
                f2bf(oacc[cb][r] * lr);
    }
}

// ---------------- launch ----------------------------------------------------
extern "C" void kernel_launch(void* const* d_in, const int* in_sizes, int n_in,
                              void* d_out, int out_size, void* d_ws, size_t ws_size,
                              hipStream_t stream) {
    const float* x  = (const float*)d_in[0];
    const float* Wq = (const float*)d_in[2];
    const float* bq = (const float*)d_in[3];
    const float* Wk = (const float*)d_in[4];
    const float* bk = (const float*)d_in[5];
    const float* Wv = (const float*)d_in[6];
    const float* bv = (const float*)d_in[7];
    const float* Wo = (const float*)d_in[8];
    const float* bo = (const float*)d_in[9];

    char* ws = (char*)d_ws;
    unsigned short* xb  = (unsigned short*)(ws);
    unsigned short* Wqb = (unsigned short*)(ws + ((size_t)16 << 20));
    unsigned short* Wkb = (unsigned short*)(ws + ((size_t)24 << 20));
    unsigned short* Wvb = (unsigned short*)(ws + ((size_t)32 << 20));
    unsigned short* Wob = (unsigned short*)(ws + ((size_t)40 << 20));
    unsigned short* Qb  = (unsigned short*)(ws + ((size_t)48 << 20));
    unsigned short* Kb  = (unsigned short*)(ws + ((size_t)64 << 20));
    unsigned short* Vtb = (unsigned short*)(ws + ((size_t)80 << 20));
    unsigned short* Ob  = (unsigned short*)(ws + ((size_t)96 << 20));

    cvt_f32_bf16<<<2048, 256, 0, stream>>>(x,  xb,  (N_TOK * D_MODEL) / 4);
    cvt_f32_bf16<<<1024, 256, 0, stream>>>(Wq, Wqb, (D_MODEL * D_MODEL) / 4);
    cvt_f32_bf16<<<1024, 256, 0, stream>>>(Wk, Wkb, (D_MODEL * D_MODEL) / 4);
    cvt_f32_bf16<<<1024, 256, 0, stream>>>(Wv, Wvb, (D_MODEL * D_MODEL) / 4);
    cvt_f32_bf16<<<1024, 256, 0, stream>>>(Wo, Wob, (D_MODEL * D_MODEL) / 4);

    gemm_bt<1, 0><<<dim3(D_MODEL / BN, N_TOK / BM), 256, 0, stream>>>(
        xb, D_MODEL, Wqb, D_MODEL, Qb, D_MODEL, bq, D_MODEL);
    gemm_bt<1, 0><<<dim3(D_MODEL / BN, N_TOK / BM), 256, 0, stream>>>(
        xb, D_MODEL, Wkb, D_MODEL, Kb, D_MODEL, bk, D_MODEL);
    gemm_bt<1, 1><<<dim3(N_TOK / BN, D_MODEL / BM), 256, 0, stream>>>(
        Wvb, D_MODEL, xb, D_MODEL, Vtb, N_TOK, bv, D_MODEL);

    attn_kernel<<<dim3(64, N_HEADS), 128, 0, stream>>>(Qb, Kb, Vtb, Ob);

    gemm_bt<0, 0><<<dim3(D_MODEL / BN, N_TOK / BM), 256, 0, stream>>>(
        Ob, D_MODEL, Wob, D_MODEL, (float*)d_out, D_MODEL, bo, D_MODEL);
}